// Round 10
// baseline (1423.049 us; speedup 1.0000x reference)
//
#include <hip/hip_runtime.h>
#include <hip/hip_bf16.h>

#define T_STEPS 128
#define BATCH   32
#define IN_DIM  512
#define H_DIM   1024
#define OUT_DIM 8192
#define KH      3072   // (K-1)*H
#define NWG     128
#define SLOT_E  32768  // elements per h slot (1024 k * 32 b)
#define NSLOT   131    // h_t stored at slot 127-t; slots 128..130 = zeros

typedef __attribute__((ext_vector_type(8))) short short8;
typedef __attribute__((ext_vector_type(4))) float f32x4;

__device__ __forceinline__ unsigned short bf16_rne(float f) {
  unsigned u = __float_as_uint(f);
  unsigned r = (u + 0x7FFFu + ((u >> 16) & 1u)) >> 16;
  return (unsigned short)r;
}

__device__ __forceinline__ void gload_lds16(const void* g, void* l) {
  __builtin_amdgcn_global_load_lds(
      (const __attribute__((address_space(1))) void*)g,
      (__attribute__((address_space(3))) void*)l, 16, 0, 0);
}

// ---------------- Wmo f32 -> bf16 ----------------
__global__ __launch_bounds__(256) void convert_kernel(
    const float* __restrict__ src, unsigned short* __restrict__ dst, int n4) {
  int i = blockIdx.x * blockDim.x + threadIdx.x;
  const int stride = gridDim.x * blockDim.x;
  for (; i < n4; i += stride) {
    float4 v = ((const float4*)src)[i];
    ushort4 o;
    o.x = bf16_rne(v.x); o.y = bf16_rne(v.y);
    o.z = bf16_rne(v.z); o.w = bf16_rne(v.w);
    ((ushort4*)dst)[i] = o;
  }
}

// ---------------- pre[t][j][b] = X@Wxh^T + bias (fp32) ---------------------
__global__ __launch_bounds__(256) void pre_kernel(
    const float* __restrict__ X, const float* __restrict__ Wxh,
    const float* __restrict__ bias, float* __restrict__ preT) {
  __shared__ float xs[32][260];
  const int tid = threadIdx.x;
  const int t  = blockIdx.x >> 4;
  const int jb = blockIdx.x & 15;
  const int b  = tid & 31;
  const int jg = tid >> 5;        // 0..7
  float acc[8];
  #pragma unroll
  for (int i = 0; i < 8; ++i) acc[i] = 0.f;

  for (int kc = 0; kc < 2; ++kc) {
    __syncthreads();
    #pragma unroll
    for (int v = tid; v < 2048; v += 256) {
      int br = v >> 6, i4 = v & 63;
      float4 x4 = *(const float4*)(X + (size_t)t*(BATCH*IN_DIM) + (size_t)br*IN_DIM + kc*256 + i4*4);
      *(float4*)&xs[br][i4*4] = x4;
    }
    __syncthreads();
    for (int i = 0; i < 256; i += 4) {
      const int k = kc*256 + i;
      float4 xv = *(const float4*)&xs[b][i];
      #pragma unroll
      for (int jj = 0; jj < 8; ++jj) {
        const int j = jb*64 + jg + jj*8;
        float4 w4 = *(const float4*)(Wxh + (size_t)j*IN_DIM + k);
        acc[jj] += xv.x*w4.x + xv.y*w4.y + xv.z*w4.z + xv.w*w4.w;
      }
    }
  }
  #pragma unroll
  for (int jj = 0; jj < 8; ++jj) {
    const int j = jb*64 + jg + jj*8;
    preT[(size_t)t*(H_DIM*BATCH) + (size_t)j*BATCH + b] = acc[jj] + bias[j];
  }
}

// ---------------- persistent MFMA recurrence, wave-level P2P flags ---------
// 128 WGs x 512 thr; WG owns 8 j rows (A rows 0-7 hi, 8-15 lo residual).
// A-fragments: 12 short8 per wave, REGISTER-resident (loaded once).
// h hi/lo bf16, B-fragment order, slot 127-t (h_cat contiguous, 128-130=0).
// Dependency: wave wv consumes k in [wv*128,(wv+1)*128) => producer WGs
// [16wv,16wv+16) = groups {2wv,2wv+1}. Each wave polls ONLY its two group
// counters of step t-1 (dk1/dk2 validated by this wave's polls at t-1,t-2).
__global__ __launch_bounds__(512, 2) void recur_kernel(
    const float* __restrict__ Whh, const float* __restrict__ preT,
    unsigned short* __restrict__ hHi, unsigned short* __restrict__ hLo,
    int* __restrict__ grp) {
  __shared__ float red[8][16][33];
  __shared__ __align__(16) unsigned short hpk_hi[32][8];
  __shared__ __align__(16) unsigned short hpk_lo[32][8];
  const int tid  = threadIdx.x;
  const int wg   = blockIdx.x;
  const int j0   = wg * 8;
  const int lane = tid & 63;
  const int wv   = tid >> 6;       // wave 0..7

  // ---- load this wave's 12 A-fragments into registers (once) ----
  // af idx: 0-3 = dk0 (ks=wv*4+i), 4-7 = dk1 (+32), 8-11 = dk2 (+64)
  short8 af[12];
  {
    const int r = lane & 15;            // A-row: 0-7 hi, 8-15 lo
    const int part = r >> 3;
    const float* wrow = Whh + (size_t)(j0 + (r & 7))*KH + (lane >> 4)*8;
    #pragma unroll
    for (int idx = 0; idx < 12; ++idx) {
      const int ks = (idx >> 2)*32 + wv*4 + (idx & 3);
      const float* wp = wrow + ks*32;
      unsigned short tmp[8];
      #pragma unroll
      for (int i = 0; i < 8; ++i) {
        const float f = wp[i];
        unsigned short v = bf16_rne(f);
        if (part) v = bf16_rne(f - __uint_as_float((unsigned)v << 16));
        tmp[i] = v;
      }
      af[idx] = *(short8*)tmp;
    }
  }

  const short8* hi8 = (const short8*)hHi;
  const short8* lo8 = (const short8*)hLo;

  for (int t = 0; t < T_STEPS; ++t) {
    const size_t sb = (size_t)(128 - t) * 4096;   // slot base, 16B units
    f32x4 a0h = {}, a0l = {}, a1h = {}, a1l = {};

    // ---- phase A: dk1 + dk2 (slots t-2/t-3, validated by earlier polls) --
    #pragma unroll
    for (int i = 0; i < 8; ++i) {
      const int ks = 32 + (i >> 2)*32 + wv*4 + (i & 3);
      const short8 a = af[4 + i];
      const size_t bidx = sb + (size_t)ks*128 + (size_t)(lane >> 4)*32 + (lane & 15);
      const short8 b0h = hi8[bidx];
      const short8 b1h = hi8[bidx + 16];
      const short8 b0l = lo8[bidx];
      const short8 b1l = lo8[bidx + 16];
      a0h = __builtin_amdgcn_mfma_f32_16x16x32_bf16(a, b0h, a0h, 0, 0, 0);
      a1h = __builtin_amdgcn_mfma_f32_16x16x32_bf16(a, b1h, a1h, 0, 0, 0);
      a0l = __builtin_amdgcn_mfma_f32_16x16x32_bf16(a, b0l, a0l, 0, 0, 0);
      a1l = __builtin_amdgcn_mfma_f32_16x16x32_bf16(a, b1l, a1l, 0, 0, 0);
    }

    // ---- prefetch pre (off the post-reduce critical path) ----
    float upre = 0.f;
    if (tid < 256)
      upre = preT[(size_t)t*(H_DIM*BATCH) + (size_t)(j0 + (tid >> 5))*BATCH + (tid & 31)];

    // ---- per-wave poll: only this wave's two producer groups, step t-1 ---
    if (t > 0) {
      const int fb = (t - 1) << 4;
      while (__hip_atomic_load(&grp[(fb + 2*wv) << 4],     __ATOMIC_RELAXED, __HIP_MEMORY_SCOPE_AGENT) +
             __hip_atomic_load(&grp[(fb + 2*wv + 1) << 4], __ATOMIC_RELAXED, __HIP_MEMORY_SCOPE_AGENT) < 16)
        __builtin_amdgcn_s_sleep(1);
      asm volatile("" ::: "memory");   // no hoisting of slot loads above poll
    }

    // ---- phase C: dk0 (h_{t-1}) ----
    #pragma unroll
    for (int i = 0; i < 4; ++i) {
      const int ks = wv*4 + i;
      const short8 a = af[i];
      const size_t bidx = sb + (size_t)ks*128 + (size_t)(lane >> 4)*32 + (lane & 15);
      const short8 b0h = hi8[bidx];
      const short8 b1h = hi8[bidx + 16];
      const short8 b0l = lo8[bidx];
      const short8 b1l = lo8[bidx + 16];
      a0h = __builtin_amdgcn_mfma_f32_16x16x32_bf16(a, b0h, a0h, 0, 0, 0);
      a1h = __builtin_amdgcn_mfma_f32_16x16x32_bf16(a, b1h, a1h, 0, 0, 0);
      a0l = __builtin_amdgcn_mfma_f32_16x16x32_bf16(a, b0l, a0l, 0, 0, 0);
      a1l = __builtin_amdgcn_mfma_f32_16x16x32_bf16(a, b1l, a1l, 0, 0, 0);
    }

    const f32x4 s0 = a0h + a0l;
    const f32x4 s1 = a1h + a1l;
    const int rr = (lane >> 4) * 4, cc = lane & 15;
    #pragma unroll
    for (int q = 0; q < 4; ++q) {
      red[wv][rr + q][cc]      = s0[q];
      red[wv][rr + q][16 + cc] = s1[q];
    }
    __syncthreads();

    if (tid < 256) {
      const int jj = tid >> 5, b = tid & 31;
      float u = upre;
      #pragma unroll
      for (int w = 0; w < 8; ++w)
        u += red[w][jj][b] + red[w][jj + 8][b];
      const float h = u > 0.f ? 1.0507009873554805f*u
                              : (1.0507009873554805f*1.6732632423543772f)*expm1f(u);
      const unsigned short hh = bf16_rne(h);
      hpk_hi[b][jj] = hh;
      hpk_lo[b][jj] = bf16_rne(h - __uint_as_float((unsigned)hh << 16));
    }
    __syncthreads();

    // ---- wave 0: h stores -> ack -> group flag (nothing after the ack) ---
    if (tid < 32) {
      const int b = tid;
      const size_t base = (size_t)(127 - t)*SLOT_E + (size_t)(j0 >> 3)*256 + (size_t)b*8;
      const unsigned long long h0 = *(const unsigned long long*)&hpk_hi[b][0];
      const unsigned long long h1 = *(const unsigned long long*)&hpk_hi[b][4];
      const unsigned long long l0 = *(const unsigned long long*)&hpk_lo[b][0];
      const unsigned long long l1 = *(const unsigned long long*)&hpk_lo[b][4];
      __hip_atomic_store((unsigned long long*)(hHi + base),     h0, __ATOMIC_RELAXED, __HIP_MEMORY_SCOPE_AGENT);
      __hip_atomic_store((unsigned long long*)(hHi + base) + 1, h1, __ATOMIC_RELAXED, __HIP_MEMORY_SCOPE_AGENT);
      __hip_atomic_store((unsigned long long*)(hLo + base),     l0, __ATOMIC_RELAXED, __HIP_MEMORY_SCOPE_AGENT);
      __hip_atomic_store((unsigned long long*)(hLo + base) + 1, l1, __ATOMIC_RELAXED, __HIP_MEMORY_SCOPE_AGENT);
      asm volatile("s_waitcnt vmcnt(0)" ::: "memory");   // h visible at L3
      if (tid == 0)
        __hip_atomic_fetch_add(&grp[((t << 4) + (wg >> 3)) << 4], 1,
                               __ATOMIC_RELAXED, __HIP_MEMORY_SCOPE_AGENT);
    }
    // no barrier: waves proceed into next step's phase A independently
  }
}

// ---------------- out = hcat @ Wmo16^T  (bf16 MFMA, 128x128 tile) ----------
// A read directly from the reversed slot buffer: row t*32+b, element k is
// hHi[(127-t)*SLOT_E + (k>>3)*256 + b*8 + (k&7)]  (slots contiguous in k).
__global__ __launch_bounds__(256) void gemm_kernel(
    const unsigned short* __restrict__ Ah, const unsigned short* __restrict__ Bm,
    float* __restrict__ C) {
  __shared__ __align__(16) unsigned short lA[4096];  // [tg 4][oct 4][b 32][e 8]
  __shared__ __align__(16) unsigned short lB[4096];  // [128 rows][32 k]
  const int tid = threadIdx.x;
  const int wg = blockIdx.x;
  // 2D-chunked XCD swizzle: XCD x owns mb [(x>>2)*16,+16), nb [(x&3)*16,+16)
  const int x = wg & 7;
  const int c = wg >> 3;
  const int mb = (x >> 2)*16 + (c & 15);
  const int nb = (x & 3)*16 + (c >> 4);
  const int lane = tid & 63;
  const int wv = tid >> 6;
  const int wm = wv >> 1, wn = wv & 1;
  const int lrow = lane & 15, lhalf = lane >> 4;
  const int rowB = tid >> 2, qB = tid & 3;
  f32x4 acc[4][4] = {};

  for (int kt = 0; kt < 128; ++kt) {
    __syncthreads();
    #pragma unroll
    for (int it = 0; it < 2; ++it) {
      // A: 8 x 1KB chunks; chunk idx -> t-group tg = idx>>1, half = idx&1
      const int idx = it*4 + wv;
      const int t  = mb*4 + (idx >> 1);
      gload_lds16(Ah + (size_t)(127 - t)*SLOT_E + kt*1024 + (idx & 1)*512 + (size_t)lane*8,
                  &lA[idx*512]);
      const int row = it*64 + rowB;
      gload_lds16(Bm + (size_t)(nb*128 + row)*4096 + kt*32 + qB*8,
                  &lB[(tid & 192)*8 + it*2048]);
    }
    __syncthreads();   // barrier drains vmcnt -> LDS valid
    short8 af[4], bf[4];
    #pragma unroll
    for (int mi = 0; mi < 4; ++mi) {
      const int tg = wm*2 + (mi >> 1);
      af[mi] = *(const short8*)&lA[tg*1024 + lhalf*256 + (lrow + (mi & 1)*16)*8];
    }
    #pragma unroll
    for (int ni = 0; ni < 4; ++ni)
      bf[ni] = *(const short8*)&lB[(wn*64 + ni*16 + lrow)*32 + lhalf*8];
    #pragma unroll
    for (int mi = 0; mi < 4; ++mi)
      #pragma unroll
      for (int ni = 0; ni < 4; ++ni)
        acc[mi][ni] = __builtin_amdgcn_mfma_f32_16x16x32_bf16(af[mi], bf[ni], acc[mi][ni], 0, 0, 0);
  }
  const int orow0 = mb*128 + wm*64 + lhalf*4;
  const int ocol0 = nb*128 + wn*64 + lrow;
  #pragma unroll
  for (int mi = 0; mi < 4; ++mi)
    #pragma unroll
    for (int ni = 0; ni < 4; ++ni)
      #pragma unroll
      for (int q = 0; q < 4; ++q)
        __builtin_nontemporal_store(acc[mi][ni][q],
            &C[(size_t)(orow0 + mi*16 + q)*OUT_DIM + ocol0 + ni*16]);
}

extern "C" void kernel_launch(void* const* d_in, const int* in_sizes, int n_in,
                              void* d_out, int out_size, void* d_ws, size_t ws_size,
                              hipStream_t stream) {
  (void)in_sizes; (void)n_in; (void)out_size; (void)ws_size;
  const float* X   = (const float*)d_in[0];
  const float* Wxh = (const float*)d_in[1];
  const float* Wxb = (const float*)d_in[2];
  const float* Whh = (const float*)d_in[3];
  const float* Wmo = (const float*)d_in[4];
  float* out = (float*)d_out;
  char* ws = (char*)d_ws;

  const size_t OFF_PRET = 0;                                               // 16.8 MB
  const size_t OFF_HHI  = OFF_PRET + (size_t)T_STEPS*H_DIM*BATCH*4;
  const size_t OFF_HLO  = OFF_HHI + (size_t)NSLOT*SLOT_E*2;                // +8.6 MB
  const size_t OFF_GRP  = OFF_HLO + (size_t)NSLOT*SLOT_E*2;                // +8.6 MB
  const size_t OFF_W16  = OFF_GRP + (size_t)T_STEPS*16*64;                 // +128 KB

  float* preT = (float*)(ws + OFF_PRET);
  unsigned short* hHi = (unsigned short*)(ws + OFF_HHI);
  unsigned short* hLo = (unsigned short*)(ws + OFF_HLO);
  int* grp  = (int*)(ws + OFF_GRP);
  unsigned short* Wmo16 = (unsigned short*)(ws + OFF_W16);

  // zero history slots (128..130) and flag lines
  hipMemsetAsync(hHi + (size_t)128*SLOT_E, 0, (size_t)3*SLOT_E*2, stream);
  hipMemsetAsync(hLo + (size_t)128*SLOT_E, 0, (size_t)3*SLOT_E*2, stream);
  hipMemsetAsync(grp, 0, (size_t)T_STEPS*16*64, stream);

  convert_kernel<<<2048, 256, 0, stream>>>(Wmo, Wmo16, (int)((size_t)OUT_DIM*4096/4));
  pre_kernel<<<2048, 256, 0, stream>>>(X, Wxh, Wxb, preT);
  recur_kernel<<<NWG, 512, 0, stream>>>(Whh, preT, hHi, hLo, grp);
  gemm_kernel<<<2048, 256, 0, stream>>>(hHi, Wmo16, out);
}

// Round 11
// 1162.637 us; speedup vs baseline: 1.2240x; 1.2240x over previous
//
#include <hip/hip_runtime.h>
#include <hip/hip_bf16.h>

#define T_STEPS 128
#define BATCH   32
#define IN_DIM  512
#define H_DIM   1024
#define OUT_DIM 8192
#define KH      3072   // (K-1)*H
#define NWG     128
#define SLOT_E  32768  // elements per h slot (1024 k * 32 b)
#define NSLOT   131    // h_t stored at slot 127-t; slots 128..130 = zeros

typedef __attribute__((ext_vector_type(8))) short short8;
typedef __attribute__((ext_vector_type(4))) float f32x4;

__device__ __forceinline__ unsigned short bf16_rne(float f) {
  unsigned u = __float_as_uint(f);
  unsigned r = (u + 0x7FFFu + ((u >> 16) & 1u)) >> 16;
  return (unsigned short)r;
}

__device__ __forceinline__ void gload_lds16(const void* g, void* l) {
  __builtin_amdgcn_global_load_lds(
      (const __attribute__((address_space(1))) void*)g,
      (__attribute__((address_space(3))) void*)l, 16, 0, 0);
}

// ---------------- Wmo f32 -> bf16 ----------------
__global__ __launch_bounds__(256) void convert_kernel(
    const float* __restrict__ src, unsigned short* __restrict__ dst, int n4) {
  int i = blockIdx.x * blockDim.x + threadIdx.x;
  const int stride = gridDim.x * blockDim.x;
  for (; i < n4; i += stride) {
    float4 v = ((const float4*)src)[i];
    ushort4 o;
    o.x = bf16_rne(v.x); o.y = bf16_rne(v.y);
    o.z = bf16_rne(v.z); o.w = bf16_rne(v.w);
    ((ushort4*)dst)[i] = o;
  }
}

// ---------------- pre[t][j][b] = X@Wxh^T + bias (fp32) ---------------------
__global__ __launch_bounds__(256) void pre_kernel(
    const float* __restrict__ X, const float* __restrict__ Wxh,
    const float* __restrict__ bias, float* __restrict__ preT) {
  __shared__ float xs[32][260];
  const int tid = threadIdx.x;
  const int t  = blockIdx.x >> 4;
  const int jb = blockIdx.x & 15;
  const int b  = tid & 31;
  const int jg = tid >> 5;        // 0..7
  float acc[8];
  #pragma unroll
  for (int i = 0; i < 8; ++i) acc[i] = 0.f;

  for (int kc = 0; kc < 2; ++kc) {
    __syncthreads();
    #pragma unroll
    for (int v = tid; v < 2048; v += 256) {
      int br = v >> 6, i4 = v & 63;
      float4 x4 = *(const float4*)(X + (size_t)t*(BATCH*IN_DIM) + (size_t)br*IN_DIM + kc*256 + i4*4);
      *(float4*)&xs[br][i4*4] = x4;
    }
    __syncthreads();
    for (int i = 0; i < 256; i += 4) {
      const int k = kc*256 + i;
      float4 xv = *(const float4*)&xs[b][i];
      #pragma unroll
      for (int jj = 0; jj < 8; ++jj) {
        const int j = jb*64 + jg + jj*8;
        float4 w4 = *(const float4*)(Wxh + (size_t)j*IN_DIM + k);
        acc[jj] += xv.x*w4.x + xv.y*w4.y + xv.z*w4.z + xv.w*w4.w;
      }
    }
  }
  #pragma unroll
  for (int jj = 0; jj < 8; ++jj) {
    const int j = jb*64 + jg + jj*8;
    preT[(size_t)t*(H_DIM*BATCH) + (size_t)j*BATCH + b] = acc[jj] + bias[j];
  }
}

// ---------------- persistent MFMA recurrence (round-9 best: 622 us) --------
template<int RN, int RD1, int RD2>
__device__ __forceinline__ void do_step(
    const int t, const int tid, const int wg, const int j0,
    const int lane, const int wv,
    const short8* __restrict__ wf, const short8* __restrict__ hi8,
    const short8* __restrict__ lo8, const float* __restrict__ preT,
    unsigned short* __restrict__ hHi, unsigned short* __restrict__ hLo,
    int* __restrict__ grp, int* __restrict__ root,
    short8 (&Rh0)[3][4], short8 (&Rh1)[3][4],
    short8 (&Rl0)[3][4], short8 (&Rl1)[3][4],
    float (&red)[8][16][33],
    unsigned short (&hpk_hi)[32][8], unsigned short (&hpk_lo)[32][8]) {
  f32x4 a0h = {}, a0l = {}, a1h = {}, a1l = {};

  // ---- phase A: dk1 + dk2 from registers (no memory) ----
  #pragma unroll
  for (int i = 0; i < 4; ++i) {
    const int ks = 32 + wv*4 + i;
    const short8 af = wf[ks*64 + lane];
    a0h = __builtin_amdgcn_mfma_f32_16x16x32_bf16(af, Rh0[RD1][i], a0h, 0, 0, 0);
    a1h = __builtin_amdgcn_mfma_f32_16x16x32_bf16(af, Rh1[RD1][i], a1h, 0, 0, 0);
    a0l = __builtin_amdgcn_mfma_f32_16x16x32_bf16(af, Rl0[RD1][i], a0l, 0, 0, 0);
    a1l = __builtin_amdgcn_mfma_f32_16x16x32_bf16(af, Rl1[RD1][i], a1l, 0, 0, 0);
  }
  #pragma unroll
  for (int i = 0; i < 4; ++i) {
    const int ks = 64 + wv*4 + i;
    const short8 af = wf[ks*64 + lane];
    a0h = __builtin_amdgcn_mfma_f32_16x16x32_bf16(af, Rh0[RD2][i], a0h, 0, 0, 0);
    a1h = __builtin_amdgcn_mfma_f32_16x16x32_bf16(af, Rh1[RD2][i], a1h, 0, 0, 0);
    a0l = __builtin_amdgcn_mfma_f32_16x16x32_bf16(af, Rl0[RD2][i], a0l, 0, 0, 0);
    a1l = __builtin_amdgcn_mfma_f32_16x16x32_bf16(af, Rl1[RD2][i], a1l, 0, 0, 0);
  }

  // ---- prefetch pre (off the post-reduce critical path) ----
  float upre = 0.f;
  if (tid < 256)
    upre = preT[(size_t)t*(H_DIM*BATCH) + (size_t)(j0 + (tid >> 5))*BATCH + (tid & 31)];

  // ---- wait for h_{t-1}: tid0 polls root, barrier broadcasts ----
  if (t > 0) {
    if (tid == 0) {
      while (__hip_atomic_load(&root[(t-1) << 4], __ATOMIC_RELAXED, __HIP_MEMORY_SCOPE_AGENT) < 16)
        __builtin_amdgcn_s_sleep(1);
    }
    __syncthreads();
    asm volatile("" ::: "memory");   // no hoisting of slot loads above poll
  }

  // ---- load fresh dk0 slot (h_{t-1}) into set RN ----
  {
    const size_t sb = (size_t)(128 - t) * 4096;   // slot base, 16B units
    #pragma unroll
    for (int i = 0; i < 4; ++i) {
      const int ks = wv*4 + i;
      const size_t bidx = sb + (size_t)ks*128 + (size_t)(lane >> 4)*32 + (lane & 15);
      Rh0[RN][i] = hi8[bidx];
      Rh1[RN][i] = hi8[bidx + 16];
      Rl0[RN][i] = lo8[bidx];
      Rl1[RN][i] = lo8[bidx + 16];
    }
  }
  // ---- phase C: dk0 MFMA ----
  #pragma unroll
  for (int i = 0; i < 4; ++i) {
    const int ks = wv*4 + i;
    const short8 af = wf[ks*64 + lane];
    a0h = __builtin_amdgcn_mfma_f32_16x16x32_bf16(af, Rh0[RN][i], a0h, 0, 0, 0);
    a1h = __builtin_amdgcn_mfma_f32_16x16x32_bf16(af, Rh1[RN][i], a1h, 0, 0, 0);
    a0l = __builtin_amdgcn_mfma_f32_16x16x32_bf16(af, Rl0[RN][i], a0l, 0, 0, 0);
    a1l = __builtin_amdgcn_mfma_f32_16x16x32_bf16(af, Rl1[RN][i], a1l, 0, 0, 0);
  }

  const f32x4 s0 = a0h + a0l;
  const f32x4 s1 = a1h + a1l;
  const int rr = (lane >> 4) * 4, cc = lane & 15;
  #pragma unroll
  for (int q = 0; q < 4; ++q) {
    red[wv][rr + q][cc]      = s0[q];
    red[wv][rr + q][16 + cc] = s1[q];
  }
  __syncthreads();

  if (tid < 256) {
    const int jj = tid >> 5, b = tid & 31;
    float u = upre;
    #pragma unroll
    for (int w = 0; w < 8; ++w)
      u += red[w][jj][b] + red[w][jj + 8][b];
    const float h = u > 0.f ? 1.0507009873554805f*u
                            : (1.0507009873554805f*1.6732632423543772f)*expm1f(u);
    const unsigned short hh = bf16_rne(h);
    hpk_hi[b][jj] = hh;
    hpk_lo[b][jj] = bf16_rne(h - __uint_as_float((unsigned)hh << 16));
  }
  __syncthreads();

  // ---- wave 0: h stores -> ack -> tree flag (nothing after the ack) ----
  if (tid < 32) {
    const int b = tid;
    const size_t base = (size_t)(127 - t)*SLOT_E + (size_t)(j0 >> 3)*256 + (size_t)b*8;
    const unsigned long long h0 = *(const unsigned long long*)&hpk_hi[b][0];
    const unsigned long long h1 = *(const unsigned long long*)&hpk_hi[b][4];
    const unsigned long long l0 = *(const unsigned long long*)&hpk_lo[b][0];
    const unsigned long long l1 = *(const unsigned long long*)&hpk_lo[b][4];
    __hip_atomic_store((unsigned long long*)(hHi + base),     h0, __ATOMIC_RELAXED, __HIP_MEMORY_SCOPE_AGENT);
    __hip_atomic_store((unsigned long long*)(hHi + base) + 1, h1, __ATOMIC_RELAXED, __HIP_MEMORY_SCOPE_AGENT);
    __hip_atomic_store((unsigned long long*)(hLo + base),     l0, __ATOMIC_RELAXED, __HIP_MEMORY_SCOPE_AGENT);
    __hip_atomic_store((unsigned long long*)(hLo + base) + 1, l1, __ATOMIC_RELAXED, __HIP_MEMORY_SCOPE_AGENT);
    asm volatile("s_waitcnt vmcnt(0)" ::: "memory");   // h visible at L3
    if (tid == 0) {
      const int g = wg >> 3;   // 16 groups of 8 WGs, private 64B lines
      if (__hip_atomic_fetch_add(&grp[((t << 4) + g) << 4], 1, __ATOMIC_RELAXED, __HIP_MEMORY_SCOPE_AGENT) == 7)
        __hip_atomic_fetch_add(&root[t << 4], 1, __ATOMIC_RELAXED, __HIP_MEMORY_SCOPE_AGENT);
    }
  }
  // no barrier: waves proceed into next step's phase A
}

__global__ __launch_bounds__(512, 2) void recur_kernel(
    const float* __restrict__ Whh, const float* __restrict__ preT,
    unsigned short* __restrict__ hHi, unsigned short* __restrict__ hLo,
    int* __restrict__ grp, int* __restrict__ root) {
  __shared__ __align__(16) unsigned short w_lds[96*64*8];  // 96 KB A-fragments
  __shared__ float red[8][16][33];
  __shared__ __align__(16) unsigned short hpk_hi[32][8];
  __shared__ __align__(16) unsigned short hpk_lo[32][8];
  const int tid  = threadIdx.x;
  const int wg   = blockIdx.x;
  const int j0   = wg * 8;
  const int lane = tid & 63;
  const int wv   = tid >> 6;       // wave 0..7

  // ---- stage Whh as hi/lo mfma A-fragments (once) ----
  for (int s = tid; s < 6144; s += 512) {
    const int ks = s >> 6, l = s & 63;
    const int r = l & 15;                 // A-row: 0-7 hi, 8-15 lo
    const int j = j0 + (r & 7);
    const int part = r >> 3;
    const int kb = ks*32 + (l >> 4)*8;
    const float* wp = Whh + (size_t)j*KH + kb;
    unsigned short tmp[8];
    #pragma unroll
    for (int i = 0; i < 8; ++i) {
      const float f = wp[i];
      unsigned short v = bf16_rne(f);
      if (part) v = bf16_rne(f - __uint_as_float((unsigned)v << 16));
      tmp[i] = v;
    }
    *(short8*)&w_lds[s*8] = *(short8*)tmp;
  }
  __syncthreads();

  const short8* wf  = (const short8*)w_lds;
  const short8* hi8 = (const short8*)hHi;
  const short8* lo8 = (const short8*)hLo;

  // rotating B-fragment register file: sets 1,2 = zero history
  short8 Rh0[3][4], Rh1[3][4], Rl0[3][4], Rl1[3][4];
  const short8 z8 = {};
  #pragma unroll
  for (int r = 1; r < 3; ++r)
    #pragma unroll
    for (int i = 0; i < 4; ++i) {
      Rh0[r][i] = z8; Rh1[r][i] = z8; Rl0[r][i] = z8; Rl1[r][i] = z8;
    }

  for (int t3 = 0; t3 < 126; t3 += 3) {
    do_step<0,2,1>(t3,   tid, wg, j0, lane, wv, wf, hi8, lo8, preT, hHi, hLo,
                   grp, root, Rh0, Rh1, Rl0, Rl1, red, hpk_hi, hpk_lo);
    do_step<1,0,2>(t3+1, tid, wg, j0, lane, wv, wf, hi8, lo8, preT, hHi, hLo,
                   grp, root, Rh0, Rh1, Rl0, Rl1, red, hpk_hi, hpk_lo);
    do_step<2,1,0>(t3+2, tid, wg, j0, lane, wv, wf, hi8, lo8, preT, hHi, hLo,
                   grp, root, Rh0, Rh1, Rl0, Rl1, red, hpk_hi, hpk_lo);
  }
  do_step<0,2,1>(126, tid, wg, j0, lane, wv, wf, hi8, lo8, preT, hHi, hLo,
                 grp, root, Rh0, Rh1, Rl0, Rl1, red, hpk_hi, hpk_lo);
  do_step<1,0,2>(127, tid, wg, j0, lane, wv, wf, hi8, lo8, preT, hHi, hLo,
                 grp, root, Rh0, Rh1, Rl0, Rl1, red, hpk_hi, hpk_lo);
}

// ---------------- out = hcat @ Wmo16^T  (bf16 MFMA, 128x128, dbuf+swz) -----
// A read directly from the reversed slot buffer (slots contiguous in k).
// B LDS rows XOR-swizzled (pre-swizzled global src + swizzled read) to kill
// the 8-way stride-64B bank conflict; 2-phase double-buffer, vmcnt(4) counted.
__global__ __launch_bounds__(256) void gemm_kernel(
    const unsigned short* __restrict__ Ah, const unsigned short* __restrict__ Bm,
    float* __restrict__ C) {
  __shared__ __align__(16) unsigned short lA[2][4096]; // [tg 4][q 4][b 32][e 8]
  __shared__ __align__(16) unsigned short lB[2][4096]; // [row 128][slot 4][e 8]
  const int tid = threadIdx.x;
  const int wg = blockIdx.x;
  // 2D-chunked XCD swizzle: XCD x owns mb [(x>>2)*16,+16), nb [(x&3)*16,+16)
  const int x = wg & 7;
  const int c = wg >> 3;
  const int mb = (x >> 2)*16 + (c & 15);
  const int nb = (x & 3)*16 + (c >> 4);
  const int lane = tid & 63;
  const int wv = tid >> 6;
  const int wm = wv >> 1, wn = wv & 1;
  const int lrow = lane & 15, lhalf = lane >> 4;
  const int rowB0 = tid >> 2, qB = tid & 3;
  f32x4 acc[4][4] = {};

#define STAGE(buf, kt) do {                                                    \
    _Pragma("unroll")                                                          \
    for (int it = 0; it < 2; ++it) {                                           \
      const int idxA = it*4 + wv;                                              \
      const int tA = mb*4 + (idxA >> 1);                                       \
      gload_lds16(Ah + (size_t)(127 - tA)*SLOT_E + (size_t)(kt)*1024           \
                     + (idxA & 1)*512 + (size_t)lane*8,                        \
                  &lA[buf][idxA*512]);                                         \
      const int rB = it*64 + rowB0;                                            \
      const int qs = qB ^ ((rB ^ (rB >> 2)) & 3);                              \
      gload_lds16(Bm + (size_t)(nb*128 + rB)*4096 + (size_t)(kt)*32 + qs*8,    \
                  &lB[buf][(tid & 192)*8 + it*2048]);                          \
    } } while (0)

  STAGE(0, 0);
  for (int kt = 0; kt < 128; ++kt) {
    const int cur = kt & 1;
    if (kt < 127) {
      STAGE(cur ^ 1, kt + 1);                       // prefetch next K-slice
      asm volatile("s_waitcnt vmcnt(4)" ::: "memory");  // cur's loads done
    } else {
      asm volatile("s_waitcnt vmcnt(0)" ::: "memory");
    }
    __syncthreads();
    short8 af[4], bf[4];
    #pragma unroll
    for (int mi = 0; mi < 4; ++mi) {
      const int tg = wm*2 + (mi >> 1);
      af[mi] = *(const short8*)&lA[cur][tg*1024 + lhalf*256 + (lrow + (mi & 1)*16)*8];
    }
    #pragma unroll
    for (int ni = 0; ni < 4; ++ni) {
      const int r = wn*64 + ni*16 + lrow;
      const int qs = lhalf ^ ((r ^ (r >> 2)) & 3);
      bf[ni] = *(const short8*)&lB[cur][r*32 + qs*8];
    }
    #pragma unroll
    for (int mi = 0; mi < 4; ++mi)
      #pragma unroll
      for (int ni = 0; ni < 4; ++ni)
        acc[mi][ni] = __builtin_amdgcn_mfma_f32_16x16x32_bf16(af[mi], bf[ni], acc[mi][ni], 0, 0, 0);
    __syncthreads();   // protect buf[cur] before it is restaged at kt+1
  }
#undef STAGE

  const int orow0 = mb*128 + wm*64 + lhalf*4;
  const int ocol0 = nb*128 + wn*64 + lrow;
  #pragma unroll
  for (int mi = 0; mi < 4; ++mi)
    #pragma unroll
    for (int ni = 0; ni < 4; ++ni)
      #pragma unroll
      for (int q = 0; q < 4; ++q)
        __builtin_nontemporal_store(acc[mi][ni][q],
            &C[(size_t)(orow0 + mi*16 + q)*OUT_DIM + ocol0 + ni*16]);
}

extern "C" void kernel_launch(void* const* d_in, const int* in_sizes, int n_in,
                              void* d_out, int out_size, void* d_ws, size_t ws_size,
                              hipStream_t stream) {
  (void)in_sizes; (void)n_in; (void)out_size; (void)ws_size;
  const float* X   = (const float*)d_in[0];
  const float* Wxh = (const float*)d_in[1];
  const float* Wxb = (const float*)d_in[2];
  const float* Whh = (const float*)d_in[3];
  const float* Wmo = (const float*)d_in[4];
  float* out = (float*)d_out;
  char* ws = (char*)d_ws;

  const size_t OFF_PRET = 0;                                               // 16.8 MB
  const size_t OFF_HHI  = OFF_PRET + (size_t)T_STEPS*H_DIM*BATCH*4;
  const size_t OFF_HLO  = OFF_HHI + (size_t)NSLOT*SLOT_E*2;                // +8.6 MB
  const size_t OFF_GRP  = OFF_HLO + (size_t)NSLOT*SLOT_E*2;                // +8.6 MB
  const size_t OFF_ROOT = OFF_GRP + (size_t)T_STEPS*16*64;                 // +128 KB
  const size_t OFF_W16  = OFF_ROOT + (size_t)T_STEPS*64;                   // +8 KB

  float* preT = (float*)(ws + OFF_PRET);
  unsigned short* hHi = (unsigned short*)(ws + OFF_HHI);
  unsigned short* hLo = (unsigned short*)(ws + OFF_HLO);
  int* grp  = (int*)(ws + OFF_GRP);
  int* root = (int*)(ws + OFF_ROOT);
  unsigned short* Wmo16 = (unsigned short*)(ws + OFF_W16);

  // zero history slots (128..130) and flag trees
  hipMemsetAsync(hHi + (size_t)128*SLOT_E, 0, (size_t)3*SLOT_E*2, stream);
  hipMemsetAsync(hLo + (size_t)128*SLOT_E, 0, (size_t)3*SLOT_E*2, stream);
  hipMemsetAsync(grp, 0, (size_t)T_STEPS*16*64 + (size_t)T_STEPS*64, stream);

  convert_kernel<<<2048, 256, 0, stream>>>(Wmo, Wmo16, (int)((size_t)OUT_DIM*4096/4));
  pre_kernel<<<2048, 256, 0, stream>>>(X, Wxh, Wxb, preT);
  recur_kernel<<<NWG, 512, 0, stream>>>(Whh, preT, hHi, hLo, grp, root);
  gemm_kernel<<<2048, 256, 0, stream>>>(hHi, Wmo16, out);
}

// Round 12
// 1133.397 us; speedup vs baseline: 1.2556x; 1.0258x over previous
//
#include <hip/hip_runtime.h>
#include <hip/hip_bf16.h>

#define T_STEPS 128
#define BATCH   32
#define IN_DIM  512
#define H_DIM   1024
#define OUT_DIM 8192
#define KH      3072   // (K-1)*H
#define NWG     128
#define SLOT_E  32768  // elements per h slot (1024 k * 32 b)
#define NSLOT   131    // h_t stored at slot 127-t; slots 128..130 = zeros

typedef __attribute__((ext_vector_type(8))) short short8;
typedef __attribute__((ext_vector_type(4))) float f32x4;

__device__ __forceinline__ unsigned short bf16_rne(float f) {
  unsigned u = __float_as_uint(f);
  unsigned r = (u + 0x7FFFu + ((u >> 16) & 1u)) >> 16;
  return (unsigned short)r;
}

__device__ __forceinline__ void gload_lds16(const void* g, void* l) {
  __builtin_amdgcn_global_load_lds(
      (const __attribute__((address_space(1))) void*)g,
      (__attribute__((address_space(3))) void*)l, 16, 0, 0);
}

// ---------------- Wmo f32 -> bf16 ----------------
__global__ __launch_bounds__(256) void convert_kernel(
    const float* __restrict__ src, unsigned short* __restrict__ dst, int n4) {
  int i = blockIdx.x * blockDim.x + threadIdx.x;
  const int stride = gridDim.x * blockDim.x;
  for (; i < n4; i += stride) {
    float4 v = ((const float4*)src)[i];
    ushort4 o;
    o.x = bf16_rne(v.x); o.y = bf16_rne(v.y);
    o.z = bf16_rne(v.z); o.w = bf16_rne(v.w);
    ((ushort4*)dst)[i] = o;
  }
}

// ---------------- pre[t][j][b] = X@Wxh^T + bias (fp32) ---------------------
__global__ __launch_bounds__(256) void pre_kernel(
    const float* __restrict__ X, const float* __restrict__ Wxh,
    const float* __restrict__ bias, float* __restrict__ preT) {
  __shared__ float xs[32][260];
  const int tid = threadIdx.x;
  const int t  = blockIdx.x >> 4;
  const int jb = blockIdx.x & 15;
  const int b  = tid & 31;
  const int jg = tid >> 5;        // 0..7
  float acc[8];
  #pragma unroll
  for (int i = 0; i < 8; ++i) acc[i] = 0.f;

  for (int kc = 0; kc < 2; ++kc) {
    __syncthreads();
    #pragma unroll
    for (int v = tid; v < 2048; v += 256) {
      int br = v >> 6, i4 = v & 63;
      float4 x4 = *(const float4*)(X + (size_t)t*(BATCH*IN_DIM) + (size_t)br*IN_DIM + kc*256 + i4*4);
      *(float4*)&xs[br][i4*4] = x4;
    }
    __syncthreads();
    for (int i = 0; i < 256; i += 4) {
      const int k = kc*256 + i;
      float4 xv = *(const float4*)&xs[b][i];
      #pragma unroll
      for (int jj = 0; jj < 8; ++jj) {
        const int j = jb*64 + jg + jj*8;
        float4 w4 = *(const float4*)(Wxh + (size_t)j*IN_DIM + k);
        acc[jj] += xv.x*w4.x + xv.y*w4.y + xv.z*w4.z + xv.w*w4.w;
      }
    }
  }
  #pragma unroll
  for (int jj = 0; jj < 8; ++jj) {
    const int j = jb*64 + jg + jj*8;
    preT[(size_t)t*(H_DIM*BATCH) + (size_t)j*BATCH + b] = acc[jj] + bias[j];
  }
}

// ---------------- persistent MFMA recurrence (R9 + replicated done-flags) --
// Arrival: 16 grp lines (8 adders each) -> rootcnt line (16 adders) -> the
// 16th arriver STORES "done" to 8 replica lines; each WG's tid0 polls
// replica wg&7 => 16 pollers/line (was 128 on one line: L3 same-line
// service-rate saturation was the hidden per-step cost).
template<int RN, int RD1, int RD2>
__device__ __forceinline__ void do_step(
    const int t, const int tid, const int wg, const int j0,
    const int lane, const int wv,
    const short8* __restrict__ wf, const short8* __restrict__ hi8,
    const short8* __restrict__ lo8, const float* __restrict__ preT,
    unsigned short* __restrict__ hHi, unsigned short* __restrict__ hLo,
    int* __restrict__ grp, int* __restrict__ rootcnt, int* __restrict__ rootrep,
    short8 (&Rh0)[3][4], short8 (&Rh1)[3][4],
    short8 (&Rl0)[3][4], short8 (&Rl1)[3][4],
    float (&red)[8][16][33],
    unsigned short (&hpk_hi)[32][8], unsigned short (&hpk_lo)[32][8]) {
  f32x4 a0h = {}, a0l = {}, a1h = {}, a1l = {};

  // ---- phase A: dk1 + dk2 from registers (no memory) ----
  #pragma unroll
  for (int i = 0; i < 4; ++i) {
    const int ks = 32 + wv*4 + i;
    const short8 af = wf[ks*64 + lane];
    a0h = __builtin_amdgcn_mfma_f32_16x16x32_bf16(af, Rh0[RD1][i], a0h, 0, 0, 0);
    a1h = __builtin_amdgcn_mfma_f32_16x16x32_bf16(af, Rh1[RD1][i], a1h, 0, 0, 0);
    a0l = __builtin_amdgcn_mfma_f32_16x16x32_bf16(af, Rl0[RD1][i], a0l, 0, 0, 0);
    a1l = __builtin_amdgcn_mfma_f32_16x16x32_bf16(af, Rl1[RD1][i], a1l, 0, 0, 0);
  }
  #pragma unroll
  for (int i = 0; i < 4; ++i) {
    const int ks = 64 + wv*4 + i;
    const short8 af = wf[ks*64 + lane];
    a0h = __builtin_amdgcn_mfma_f32_16x16x32_bf16(af, Rh0[RD2][i], a0h, 0, 0, 0);
    a1h = __builtin_amdgcn_mfma_f32_16x16x32_bf16(af, Rh1[RD2][i], a1h, 0, 0, 0);
    a0l = __builtin_amdgcn_mfma_f32_16x16x32_bf16(af, Rl0[RD2][i], a0l, 0, 0, 0);
    a1l = __builtin_amdgcn_mfma_f32_16x16x32_bf16(af, Rl1[RD2][i], a1l, 0, 0, 0);
  }

  // ---- prefetch pre (off the post-reduce critical path) ----
  float upre = 0.f;
  if (tid < 256)
    upre = preT[(size_t)t*(H_DIM*BATCH) + (size_t)(j0 + (tid >> 5))*BATCH + (tid & 31)];

  // ---- wait for h_{t-1}: tid0 polls its replica line, barrier broadcasts --
  if (t > 0) {
    if (tid == 0) {
      while (!__hip_atomic_load(&rootrep[(((t-1) << 3) + (wg & 7)) << 4],
                                __ATOMIC_RELAXED, __HIP_MEMORY_SCOPE_AGENT))
        __builtin_amdgcn_s_sleep(2);
    }
    __syncthreads();
    asm volatile("" ::: "memory");   // no hoisting of slot loads above poll
  }

  // ---- load fresh dk0 slot (h_{t-1}) into set RN ----
  {
    const size_t sb = (size_t)(128 - t) * 4096;   // slot base, 16B units
    #pragma unroll
    for (int i = 0; i < 4; ++i) {
      const int ks = wv*4 + i;
      const size_t bidx = sb + (size_t)ks*128 + (size_t)(lane >> 4)*32 + (lane & 15);
      Rh0[RN][i] = hi8[bidx];
      Rh1[RN][i] = hi8[bidx + 16];
      Rl0[RN][i] = lo8[bidx];
      Rl1[RN][i] = lo8[bidx + 16];
    }
  }
  // ---- phase C: dk0 MFMA ----
  #pragma unroll
  for (int i = 0; i < 4; ++i) {
    const int ks = wv*4 + i;
    const short8 af = wf[ks*64 + lane];
    a0h = __builtin_amdgcn_mfma_f32_16x16x32_bf16(af, Rh0[RN][i], a0h, 0, 0, 0);
    a1h = __builtin_amdgcn_mfma_f32_16x16x32_bf16(af, Rh1[RN][i], a1h, 0, 0, 0);
    a0l = __builtin_amdgcn_mfma_f32_16x16x32_bf16(af, Rl0[RN][i], a0l, 0, 0, 0);
    a1l = __builtin_amdgcn_mfma_f32_16x16x32_bf16(af, Rl1[RN][i], a1l, 0, 0, 0);
  }

  const f32x4 s0 = a0h + a0l;
  const f32x4 s1 = a1h + a1l;
  const int rr = (lane >> 4) * 4, cc = lane & 15;
  #pragma unroll
  for (int q = 0; q < 4; ++q) {
    red[wv][rr + q][cc]      = s0[q];
    red[wv][rr + q][16 + cc] = s1[q];
  }
  __syncthreads();

  if (tid < 256) {
    const int jj = tid >> 5, b = tid & 31;
    float u = upre;
    #pragma unroll
    for (int w = 0; w < 8; ++w)
      u += red[w][jj][b] + red[w][jj + 8][b];
    const float h = u > 0.f ? 1.0507009873554805f*u
                            : (1.0507009873554805f*1.6732632423543772f)*expm1f(u);
    const unsigned short hh = bf16_rne(h);
    hpk_hi[b][jj] = hh;
    hpk_lo[b][jj] = bf16_rne(h - __uint_as_float((unsigned)hh << 16));
  }
  __syncthreads();

  // ---- wave 0: h stores -> ack -> grp -> rootcnt -> 8 replica stores ----
  if (tid < 32) {
    const int b = tid;
    const size_t base = (size_t)(127 - t)*SLOT_E + (size_t)(j0 >> 3)*256 + (size_t)b*8;
    const unsigned long long h0 = *(const unsigned long long*)&hpk_hi[b][0];
    const unsigned long long h1 = *(const unsigned long long*)&hpk_hi[b][4];
    const unsigned long long l0 = *(const unsigned long long*)&hpk_lo[b][0];
    const unsigned long long l1 = *(const unsigned long long*)&hpk_lo[b][4];
    __hip_atomic_store((unsigned long long*)(hHi + base),     h0, __ATOMIC_RELAXED, __HIP_MEMORY_SCOPE_AGENT);
    __hip_atomic_store((unsigned long long*)(hHi + base) + 1, h1, __ATOMIC_RELAXED, __HIP_MEMORY_SCOPE_AGENT);
    __hip_atomic_store((unsigned long long*)(hLo + base),     l0, __ATOMIC_RELAXED, __HIP_MEMORY_SCOPE_AGENT);
    __hip_atomic_store((unsigned long long*)(hLo + base) + 1, l1, __ATOMIC_RELAXED, __HIP_MEMORY_SCOPE_AGENT);
    if (t < T_STEPS - 1) {
      asm volatile("s_waitcnt vmcnt(0)" ::: "memory");   // h visible at L3
      if (tid == 0) {
        const int g = wg >> 3;   // 16 groups of 8 WGs, private 64B lines
        if (__hip_atomic_fetch_add(&grp[((t << 4) + g) << 4], 1, __ATOMIC_RELAXED, __HIP_MEMORY_SCOPE_AGENT) == 7) {
          if (__hip_atomic_fetch_add(&rootcnt[t << 4], 1, __ATOMIC_RELAXED, __HIP_MEMORY_SCOPE_AGENT) == 15) {
            #pragma unroll
            for (int r = 0; r < 8; ++r)
              __hip_atomic_store(&rootrep[((t << 3) + r) << 4], 1,
                                 __ATOMIC_RELAXED, __HIP_MEMORY_SCOPE_AGENT);
          }
        }
      }
    }
  }
  // no barrier: waves proceed into next step's phase A
}

__global__ __launch_bounds__(512, 2) void recur_kernel(
    const float* __restrict__ Whh, const float* __restrict__ preT,
    unsigned short* __restrict__ hHi, unsigned short* __restrict__ hLo,
    int* __restrict__ grp, int* __restrict__ rootcnt, int* __restrict__ rootrep) {
  __shared__ __align__(16) unsigned short w_lds[96*64*8];  // 96 KB A-fragments
  __shared__ float red[8][16][33];
  __shared__ __align__(16) unsigned short hpk_hi[32][8];
  __shared__ __align__(16) unsigned short hpk_lo[32][8];
  const int tid  = threadIdx.x;
  const int wg   = blockIdx.x;
  const int j0   = wg * 8;
  const int lane = tid & 63;
  const int wv   = tid >> 6;       // wave 0..7

  // ---- stage Whh as hi/lo mfma A-fragments (once) ----
  for (int s = tid; s < 6144; s += 512) {
    const int ks = s >> 6, l = s & 63;
    const int r = l & 15;                 // A-row: 0-7 hi, 8-15 lo
    const int j = j0 + (r & 7);
    const int part = r >> 3;
    const int kb = ks*32 + (l >> 4)*8;
    const float* wp = Whh + (size_t)j*KH + kb;
    unsigned short tmp[8];
    #pragma unroll
    for (int i = 0; i < 8; ++i) {
      const float f = wp[i];
      unsigned short v = bf16_rne(f);
      if (part) v = bf16_rne(f - __uint_as_float((unsigned)v << 16));
      tmp[i] = v;
    }
    *(short8*)&w_lds[s*8] = *(short8*)tmp;
  }
  __syncthreads();

  const short8* wf  = (const short8*)w_lds;
  const short8* hi8 = (const short8*)hHi;
  const short8* lo8 = (const short8*)hLo;

  // rotating B-fragment register file: sets 1,2 = zero history
  short8 Rh0[3][4], Rh1[3][4], Rl0[3][4], Rl1[3][4];
  const short8 z8 = {};
  #pragma unroll
  for (int r = 1; r < 3; ++r)
    #pragma unroll
    for (int i = 0; i < 4; ++i) {
      Rh0[r][i] = z8; Rh1[r][i] = z8; Rl0[r][i] = z8; Rl1[r][i] = z8;
    }

  for (int t3 = 0; t3 < 126; t3 += 3) {
    do_step<0,2,1>(t3,   tid, wg, j0, lane, wv, wf, hi8, lo8, preT, hHi, hLo,
                   grp, rootcnt, rootrep, Rh0, Rh1, Rl0, Rl1, red, hpk_hi, hpk_lo);
    do_step<1,0,2>(t3+1, tid, wg, j0, lane, wv, wf, hi8, lo8, preT, hHi, hLo,
                   grp, rootcnt, rootrep, Rh0, Rh1, Rl0, Rl1, red, hpk_hi, hpk_lo);
    do_step<2,1,0>(t3+2, tid, wg, j0, lane, wv, wf, hi8, lo8, preT, hHi, hLo,
                   grp, rootcnt, rootrep, Rh0, Rh1, Rl0, Rl1, red, hpk_hi, hpk_lo);
  }
  do_step<0,2,1>(126, tid, wg, j0, lane, wv, wf, hi8, lo8, preT, hHi, hLo,
                 grp, rootcnt, rootrep, Rh0, Rh1, Rl0, Rl1, red, hpk_hi, hpk_lo);
  do_step<1,0,2>(127, tid, wg, j0, lane, wv, wf, hi8, lo8, preT, hHi, hLo,
                 grp, rootcnt, rootrep, Rh0, Rh1, Rl0, Rl1, red, hpk_hi, hpk_lo);
}

// ---------------- out = hcat @ Wmo16^T  (bf16 MFMA, 128x128, dbuf+swz) -----
__global__ __launch_bounds__(256) void gemm_kernel(
    const unsigned short* __restrict__ Ah, const unsigned short* __restrict__ Bm,
    float* __restrict__ C) {
  __shared__ __align__(16) unsigned short lA[2][4096]; // [tg 4][q 4][b 32][e 8]
  __shared__ __align__(16) unsigned short lB[2][4096]; // [row 128][slot 4][e 8]
  const int tid = threadIdx.x;
  const int wg = blockIdx.x;
  // 2D-chunked XCD swizzle: XCD x owns mb [(x>>2)*16,+16), nb [(x&3)*16,+16)
  const int x = wg & 7;
  const int c = wg >> 3;
  const int mb = (x >> 2)*16 + (c & 15);
  const int nb = (x & 3)*16 + (c >> 4);
  const int lane = tid & 63;
  const int wv = tid >> 6;
  const int wm = wv >> 1, wn = wv & 1;
  const int lrow = lane & 15, lhalf = lane >> 4;
  const int rowB0 = tid >> 2, qB = tid & 3;
  f32x4 acc[4][4] = {};

#define STAGE(buf, kt) do {                                                    \
    _Pragma("unroll")                                                          \
    for (int it = 0; it < 2; ++it) {                                           \
      const int idxA = it*4 + wv;                                              \
      const int tA = mb*4 + (idxA >> 1);                                       \
      gload_lds16(Ah + (size_t)(127 - tA)*SLOT_E + (size_t)(kt)*1024           \
                     + (idxA & 1)*512 + (size_t)lane*8,                        \
                  &lA[buf][idxA*512]);                                         \
      const int rB = it*64 + rowB0;                                            \
      const int qs = qB ^ ((rB ^ (rB >> 2)) & 3);                              \
      gload_lds16(Bm + (size_t)(nb*128 + rB)*4096 + (size_t)(kt)*32 + qs*8,    \
                  &lB[buf][(tid & 192)*8 + it*2048]);                          \
    } } while (0)

  STAGE(0, 0);
  for (int kt = 0; kt < 128; ++kt) {
    const int cur = kt & 1;
    if (kt < 127) {
      STAGE(cur ^ 1, kt + 1);                       // prefetch next K-slice
      asm volatile("s_waitcnt vmcnt(4)" ::: "memory");  // cur's loads done
    } else {
      asm volatile("s_waitcnt vmcnt(0)" ::: "memory");
    }
    __syncthreads();
    short8 af[4], bf[4];
    #pragma unroll
    for (int mi = 0; mi < 4; ++mi) {
      const int tg = wm*2 + (mi >> 1);
      af[mi] = *(const short8*)&lA[cur][tg*1024 + lhalf*256 + (lrow + (mi & 1)*16)*8];
    }
    #pragma unroll
    for (int ni = 0; ni < 4; ++ni) {
      const int r = wn*64 + ni*16 + lrow;
      const int qs = lhalf ^ ((r ^ (r >> 2)) & 3);
      bf[ni] = *(const short8*)&lB[cur][r*32 + qs*8];
    }
    #pragma unroll
    for (int mi = 0; mi < 4; ++mi)
      #pragma unroll
      for (int ni = 0; ni < 4; ++ni)
        acc[mi][ni] = __builtin_amdgcn_mfma_f32_16x16x32_bf16(af[mi], bf[ni], acc[mi][ni], 0, 0, 0);
    __syncthreads();   // protect buf[cur] before it is restaged at kt+1
  }
#undef STAGE

  const int orow0 = mb*128 + wm*64 + lhalf*4;
  const int ocol0 = nb*128 + wn*64 + lrow;
  #pragma unroll
  for (int mi = 0; mi < 4; ++mi)
    #pragma unroll
    for (int ni = 0; ni < 4; ++ni)
      #pragma unroll
      for (int q = 0; q < 4; ++q)
        __builtin_nontemporal_store(acc[mi][ni][q],
            &C[(size_t)(orow0 + mi*16 + q)*OUT_DIM + ocol0 + ni*16]);
}

extern "C" void kernel_launch(void* const* d_in, const int* in_sizes, int n_in,
                              void* d_out, int out_size, void* d_ws, size_t ws_size,
                              hipStream_t stream) {
  (void)in_sizes; (void)n_in; (void)out_size; (void)ws_size;
  const float* X   = (const float*)d_in[0];
  const float* Wxh = (const float*)d_in[1];
  const float* Wxb = (const float*)d_in[2];
  const float* Whh = (const float*)d_in[3];
  const float* Wmo = (const float*)d_in[4];
  float* out = (float*)d_out;
  char* ws = (char*)d_ws;

  const size_t OFF_PRET = 0;                                               // 16.8 MB
  const size_t OFF_HHI  = OFF_PRET + (size_t)T_STEPS*H_DIM*BATCH*4;
  const size_t OFF_HLO  = OFF_HHI + (size_t)NSLOT*SLOT_E*2;                // +8.6 MB
  const size_t OFF_GRP  = OFF_HLO + (size_t)NSLOT*SLOT_E*2;                // +8.6 MB
  const size_t OFF_RCNT = OFF_GRP + (size_t)T_STEPS*16*64;                 // +128 KB
  const size_t OFF_RREP = OFF_RCNT + (size_t)T_STEPS*64;                   // +8 KB
  const size_t OFF_W16  = OFF_RREP + (size_t)T_STEPS*8*64;                 // +64 KB

  float* preT = (float*)(ws + OFF_PRET);
  unsigned short* hHi = (unsigned short*)(ws + OFF_HHI);
  unsigned short* hLo = (unsigned short*)(ws + OFF_HLO);
  int* grp     = (int*)(ws + OFF_GRP);
  int* rootcnt = (int*)(ws + OFF_RCNT);
  int* rootrep = (int*)(ws + OFF_RREP);
  unsigned short* Wmo16 = (unsigned short*)(ws + OFF_W16);

  // zero history slots (128..130) and all flag lines (grp+rootcnt+rootrep)
  hipMemsetAsync(hHi + (size_t)128*SLOT_E, 0, (size_t)3*SLOT_E*2, stream);
  hipMemsetAsync(hLo + (size_t)128*SLOT_E, 0, (size_t)3*SLOT_E*2, stream);
  hipMemsetAsync(grp, 0, (size_t)T_STEPS*16*64 + (size_t)T_STEPS*64 + (size_t)T_STEPS*8*64, stream);

  convert_kernel<<<2048, 256, 0, stream>>>(Wmo, Wmo16, (int)((size_t)OUT_DIM*4096/4));
  pre_kernel<<<2048, 256, 0, stream>>>(X, Wxh, Wxb, preT);
  recur_kernel<<<NWG, 512, 0, stream>>>(Whh, preT, hHi, hLo, grp, rootcnt, rootrep);
  gemm_kernel<<<2048, 256, 0, stream>>>(hHi, Wmo16, out);
}